// Round 25
// baseline (164.595 us; speedup 1.0000x reference)
//
#include <hip/hip_runtime.h>
#include <stdint.h>
#include <limits.h>

// StackMachineCell — fused producer/consumer, pop-only stack read (round 25).
// r24 win (nt stores: 150->137us, eviction confirmed). Remaining chain:
// LUT load + extract + npn + ds_bpermute(60cy) EVERY step. Key algebra:
// the stack read is needed only on POP (~3%): PUSH -> r_new = act-2
// (immediate); NOOP -> r_new = r (invariant r == stack[ptr], holds through
// all transitions incl. clamps). So: branch the bpermute out; next LUT index
// (ns, r_new, v_{t+1}) computable ~20cy after the LUT value -> chain becomes
// back-to-back LUT loads (~250cy non-forced, ~60 forced). Trajectory
// bit-identical (case equivalence with rr = stack[npn]).
// Everything else identical to r24 (PASSED, absmax 0.0009765625).
// ws: Mm32@0 | Ms32@17408 | Mb32@50176 | MmT@115712 | MsT@133120 |
//     lut@165888  (total 690176 B; guarded).

#define TT 512
#define BB 512
#define HH 128
#define NSs 64
#define NMm 34
#define NBb 128

typedef unsigned short u16;
typedef float f2 __attribute__((ext_vector_type(2)));

// ---- precompute M tables (f64 accumulate, f32 store; + transposed copies)
__global__ __launch_bounds__(256) void precompute_M(
    const float* __restrict__ embed,
    const float* __restrict__ Wm, const float* __restrict__ bm,
    const float* __restrict__ Wb, const float* __restrict__ bb,
    const float* __restrict__ Ws, const float* __restrict__ bs,
    float* __restrict__ Mm32, float* __restrict__ Ms32,
    float* __restrict__ Mb32, float* __restrict__ MmT,
    float* __restrict__ MsT) {
  __shared__ double e[HH];
  const int v = blockIdx.x;
  const int tid = threadIdx.x;  // 256
  if (tid < HH) e[tid] = (double)embed[v * HH + tid];
  __syncthreads();
  if (tid < NMm) {
    const int j = tid;
    double acc = 0.0;
    for (int h = 0; h < HH; ++h) acc += e[h] * (double)Wm[h * NMm + j];
    const float r = (float)(acc + (double)bm[j]);
    Mm32[v * NMm + j] = r;
    MmT[j * 128 + v] = r;
  } else if (tid < NMm + NSs) {
    const int j = tid - NMm;
    double acc = 0.0;
    for (int h = 0; h < HH; ++h) acc += e[h] * (double)Ws[h * NSs + j];
    const float r = (float)(acc + (double)bs[j]);
    Ms32[v * NSs + j] = r;
    MsT[j * 128 + v] = r;
  } else if (tid < NMm + NSs + NBb) {
    const int j = tid - NMm - NSs;
    double acc = 0.0;
    for (int h = 0; h < HH; ++h) acc += e[h] * (double)Wb[h * NBb + j];
    Mb32[v * NBb + j] = (float)(acc + (double)bb[j]);
  }
}

// ---- build decision LUT: block = (s,r) pair, thread = v. Bit-identical
// arithmetic to r12-r24. Layout lut[(s*32+r)*128 + v].
__global__ __launch_bounds__(128) void build_lut(
    const float* __restrict__ Wm, const float* __restrict__ Ws,
    const float* __restrict__ MmT, const float* __restrict__ MsT,
    u16* __restrict__ lut) {
  __shared__ float wms[NMm], wmr[NMm], wss[NSs], wsr[NSs];  // 784 B
  const int s = blockIdx.x >> 5;    // 0..63
  const int r = blockIdx.x & 31;    // 0..31
  const int tid = threadIdx.x;      // 128 = one v per thread
  if (tid < NMm) {
    wms[tid] = Wm[(128 + s) * NMm + tid];
    wmr[tid] = Wm[(192 + r) * NMm + tid];
  }
  if (tid < NSs) {
    wss[tid] = Ws[(128 + s) * NSs + tid];
    wsr[tid] = Ws[(192 + r) * NSs + tid];
  }
  __syncthreads();

  const int v = tid;
  int bestm = INT_MIN, act = 0;
#pragma unroll
  for (int j = 0; j < NMm; ++j) {
    const double val = (double)MmT[j * 128 + v] + (double)wms[j] + (double)wmr[j];
    const int iv = (int)(val * 67108864.0);
    if (iv > bestm) { bestm = iv; act = j; }
  }
  int bests = INT_MIN, ns = 0;
#pragma unroll
  for (int j = 0; j < NSs; ++j) {
    const double val = (double)MsT[j * 128 + v] + (double)wss[j] + (double)wsr[j];
    const int iv = (int)(val * 67108864.0);
    if (iv > bests) { bests = iv; ns = j; }
  }
  lut[(unsigned)blockIdx.x * 128 + v] = (u16)(act | (ns << 6));
}

// ---- fused: 256 blocks x 512 threads. Waves 0-1 = producer chains
// (setprio 1, pop-only stack read); waves 2-7 = consumers (3 per chain,
// rows t mod 3, sleep-4 backoff, non-temporal stores). LDS handoff.
__global__ __launch_bounds__(512, 1) void sm_fused(
    const int* __restrict__ x, const int* __restrict__ tact,
    const int* __restrict__ tstate, const int* __restrict__ forc,
    const u16* __restrict__ lut,
    const float* __restrict__ Wm, const float* __restrict__ Wb,
    const float* __restrict__ Ws,
    const float* __restrict__ Mm32, const float* __restrict__ Ms32,
    const float* __restrict__ Mb32, float* __restrict__ out) {
  __shared__ unsigned sPk[2][TT];              // 4096 B
  __shared__ volatile u16 trajL[2][TT];        // 2048 B
  __shared__ volatile unsigned cnt[2];         //    8 B
  const int tid = threadIdx.x;
  const int base = blockIdx.x * 2;
  if (tid < 2) cnt[tid] = 0;
  for (int i = tid; i < 2 * TT; i += 512) {
    const int c = i >> 9, t = i & (TT - 1);
    const int g = t * BB + base + c;
    sPk[c][t] = (unsigned)x[g] | ((unsigned)tact[g] << 8) |
                ((unsigned)tstate[g] << 16) | ((unsigned)forc[g] << 24);
  }
  __syncthreads();  // last barrier; roles diverge below

  const int lane = tid & 63;
  const int w = tid >> 6;

  if (w < 2) {
    // ===== producer: pop-only stack read; trajectory bit-identical =======
    __builtin_amdgcn_s_setprio(1);
    const int c = w;
    int stackv = 0;  // lane i holds stack[i]; invariant: rr == stackv[ptr]
    int ptr = 0, rr = 0, s = 0;
    unsigned p0 = sPk[c][0], p1 = sPk[c][1], p2 = sPk[c][2];

    for (int t = 0; t < TT; ++t) {
      const unsigned p3 = sPk[c][t + 3 < TT ? t + 3 : TT - 1];
      const unsigned pk_s = __builtin_amdgcn_readfirstlane(p0);

      if (lane == 0) trajL[c][t] = (u16)(s | (rr << 8));  // carry-in (s,r)

      int act, ns;
      if (pk_s >> 24) {  // forced: extract from VGPR p0, no LUT
        act = (int)((p0 >> 8) & 63u);
        ns = (int)((p0 >> 16) & 63u);
      } else {
        const int idx = s * 4096 + rr * 128 + (int)(p0 & 127u);
        const int lv = lut[idx];  // the chain: back-to-back LUT loads
        act = lv & 63;
        ns = (lv >> 6) & 63;
      }

      const bool ispush = act >= 2;
      const bool ispop = act == 1;
      int npn = ptr + (ispush ? 1 : 0) - (ispop ? 1 : 0);
      npn = npn < 0 ? 0 : (npn > 63 ? 63 : npn);
      if (ispush) {            // r_new = pushed sym, no stack read
        if (lane == npn) stackv = act - 2;
        rr = act - 2;
      } else if (ispop) {      // rare (~3%): the only stack read
        const int npn_s = __builtin_amdgcn_readfirstlane(npn);
        rr = __builtin_amdgcn_readlane(stackv, npn_s);
      }                        // noop: rr unchanged (== stackv[ptr])
      ptr = npn;
      s = ns;

      if ((t & 7) == 7) {  // publish progress (single writer, monotonic)
        __threadfence_block();
        if (lane == 0) cnt[c] = (unsigned)(t + 1);
      }
      p0 = p1; p1 = p2; p2 = p3;
    }
  } else {
    // ======= consumer: 3 waves per chain, rows t = j, j+3, ... ==========
    const int c = (w - 2) & 1;
    const int j = (w - 2) >> 1;   // 0,1,2
    const int b = base + c;
    float* outLM = out;                                  // [T,B,34]
    float* outLB = out + (size_t)TT * BB * NMm;          // [T,B,128]
    float* outLS = out + (size_t)TT * BB * (NMm + NBb);  // [T,B,64]

    for (int t = j; t < TT; t += 3) {
      while (cnt[c] <= (unsigned)t) __builtin_amdgcn_s_sleep(4);  // backoff
      const unsigned pk = sPk[c][t];
      const int xv = (int)(pk & 127u);
      const int pr = trajL[c][t];
      const int s = pr & 255;
      const int r = pr >> 8;
      const int rs = 128 + s, rr = 192 + r;
      const int row = t * BB + b;
      if (lane < NMm)
        __builtin_nontemporal_store(
            Mm32[xv * NMm + lane] + Wm[rs * NMm + lane] + Wm[rr * NMm + lane],
            &outLM[(size_t)row * NMm + lane]);
      __builtin_nontemporal_store(
          Ms32[xv * NSs + lane] + Ws[rs * NSs + lane] + Ws[rr * NSs + lane],
          &outLS[(size_t)row * NSs + lane]);
      const f2 mb  = *(const f2*)&Mb32[xv * NBb + 2 * lane];
      const f2 wbs = *(const f2*)&Wb[rs * NBb + 2 * lane];
      const f2 wbr = *(const f2*)&Wb[rr * NBb + 2 * lane];
      f2 o;
      o.x = mb.x + wbs.x + wbr.x;   // same per-element add order as r14-r24
      o.y = mb.y + wbs.y + wbr.y;
      __builtin_nontemporal_store(o, (f2*)&outLB[(size_t)row * NBb + 2 * lane]);
    }
  }
}

extern "C" void kernel_launch(void* const* d_in, const int* in_sizes, int n_in,
                              void* d_out, int out_size, void* d_ws, size_t ws_size,
                              hipStream_t stream) {
  if (ws_size < 690176) return;  // signature: absmax 0.3457 -> ws too small

  const int* x     = (const int*)d_in[0];
  const int* tactp = (const int*)d_in[1];
  const int* tstp  = (const int*)d_in[2];
  const int* forcp = (const int*)d_in[3];
  const float* embed = (const float*)d_in[4];
  const float* Wm = (const float*)d_in[5];
  const float* bm = (const float*)d_in[6];
  const float* Wb = (const float*)d_in[7];
  const float* bb = (const float*)d_in[8];
  const float* Ws = (const float*)d_in[9];
  const float* bs = (const float*)d_in[10];

  char* wsp = (char*)d_ws;
  float* Mm32 = (float*)(wsp);            //  17408 B
  float* Ms32 = (float*)(wsp + 17408);    //  32768 B
  float* Mb32 = (float*)(wsp + 50176);    //  65536 B
  float* MmT  = (float*)(wsp + 115712);   //  17408 B
  float* MsT  = (float*)(wsp + 133120);   //  32768 B
  u16*   lut  = (u16*)(wsp + 165888);     // 524288 B -> total 690176 B

  precompute_M<<<128, 256, 0, stream>>>(embed, Wm, bm, Wb, bb, Ws, bs,
                                        Mm32, Ms32, Mb32, MmT, MsT);
  build_lut<<<2048, 128, 0, stream>>>(Wm, Ws, MmT, MsT, lut);
  sm_fused<<<256, 512, 0, stream>>>(x, tactp, tstp, forcp, lut,
                                    Wm, Wb, Ws, Mm32, Ms32, Mb32,
                                    (float*)d_out);
}

// Round 26
// 151.959 us; speedup vs baseline: 1.0832x; 1.0832x over previous
//
#include <hip/hip_runtime.h>
#include <stdint.h>
#include <limits.h>

// StackMachineCell — fused producer/consumer, flag-based handoff (round 26).
// r25 regressed (pop-only branch: 137->145us) -> revert to r24's producer
// (unconditional ds_bpermute, best measured). This round removes the publish
// machinery from the chain: trajL[t] itself is the flag (init 0xFFFF, an
// impossible (s|r<<8) value; producer's per-step volatile ds_write IS the
// publish; consumers spin on !=0xFFFF). No cnt, no threadfence (was a full
// vmcnt/lgkmcnt drain every 8 steps), per-row release (was 8-step batched).
// Also 1P+7C per block (512 blocks x 512t, 1 chain/block): consumer
// throughput/chain x2.3, tail overlap. Consumer math + nt stores unchanged.
// Trajectory bit-identical to r24 (PASSED, absmax 0.0009765625).
// ws: Mm32@0 | Ms32@17408 | Mb32@50176 | MmT@115712 | MsT@133120 |
//     lut@165888  (total 690176 B; guarded).

#define TT 512
#define BB 512
#define HH 128
#define NSs 64
#define NMm 34
#define NBb 128

typedef unsigned short u16;
typedef float f2 __attribute__((ext_vector_type(2)));

// ---- precompute M tables (f64 accumulate, f32 store; + transposed copies)
__global__ __launch_bounds__(256) void precompute_M(
    const float* __restrict__ embed,
    const float* __restrict__ Wm, const float* __restrict__ bm,
    const float* __restrict__ Wb, const float* __restrict__ bb,
    const float* __restrict__ Ws, const float* __restrict__ bs,
    float* __restrict__ Mm32, float* __restrict__ Ms32,
    float* __restrict__ Mb32, float* __restrict__ MmT,
    float* __restrict__ MsT) {
  __shared__ double e[HH];
  const int v = blockIdx.x;
  const int tid = threadIdx.x;  // 256
  if (tid < HH) e[tid] = (double)embed[v * HH + tid];
  __syncthreads();
  if (tid < NMm) {
    const int j = tid;
    double acc = 0.0;
    for (int h = 0; h < HH; ++h) acc += e[h] * (double)Wm[h * NMm + j];
    const float r = (float)(acc + (double)bm[j]);
    Mm32[v * NMm + j] = r;
    MmT[j * 128 + v] = r;
  } else if (tid < NMm + NSs) {
    const int j = tid - NMm;
    double acc = 0.0;
    for (int h = 0; h < HH; ++h) acc += e[h] * (double)Ws[h * NSs + j];
    const float r = (float)(acc + (double)bs[j]);
    Ms32[v * NSs + j] = r;
    MsT[j * 128 + v] = r;
  } else if (tid < NMm + NSs + NBb) {
    const int j = tid - NMm - NSs;
    double acc = 0.0;
    for (int h = 0; h < HH; ++h) acc += e[h] * (double)Wb[h * NBb + j];
    Mb32[v * NBb + j] = (float)(acc + (double)bb[j]);
  }
}

// ---- build decision LUT: block = (s,r) pair, thread = v. Bit-identical
// arithmetic to r12-r25. Layout lut[(s*32+r)*128 + v].
__global__ __launch_bounds__(128) void build_lut(
    const float* __restrict__ Wm, const float* __restrict__ Ws,
    const float* __restrict__ MmT, const float* __restrict__ MsT,
    u16* __restrict__ lut) {
  __shared__ float wms[NMm], wmr[NMm], wss[NSs], wsr[NSs];  // 784 B
  const int s = blockIdx.x >> 5;    // 0..63
  const int r = blockIdx.x & 31;    // 0..31
  const int tid = threadIdx.x;      // 128 = one v per thread
  if (tid < NMm) {
    wms[tid] = Wm[(128 + s) * NMm + tid];
    wmr[tid] = Wm[(192 + r) * NMm + tid];
  }
  if (tid < NSs) {
    wss[tid] = Ws[(128 + s) * NSs + tid];
    wsr[tid] = Ws[(192 + r) * NSs + tid];
  }
  __syncthreads();

  const int v = tid;
  int bestm = INT_MIN, act = 0;
#pragma unroll
  for (int j = 0; j < NMm; ++j) {
    const double val = (double)MmT[j * 128 + v] + (double)wms[j] + (double)wmr[j];
    const int iv = (int)(val * 67108864.0);
    if (iv > bestm) { bestm = iv; act = j; }
  }
  int bests = INT_MIN, ns = 0;
#pragma unroll
  for (int j = 0; j < NSs; ++j) {
    const double val = (double)MsT[j * 128 + v] + (double)wss[j] + (double)wsr[j];
    const int iv = (int)(val * 67108864.0);
    if (iv > bests) { bests = iv; ns = j; }
  }
  lut[(unsigned)blockIdx.x * 128 + v] = (u16)(act | (ns << 6));
}

// ---- fused: 512 blocks x 512 threads, ONE chain per block.
// Wave 0 = producer (r24 chain verbatim, setprio 1); waves 1-7 = consumers
// (rows t mod 7, sleep-4 backoff, non-temporal stores). trajL doubles as
// the progress flag (0xFFFF = not ready; legal values <= 0x1F3F).
__global__ __launch_bounds__(512, 1) void sm_fused(
    const int* __restrict__ x, const int* __restrict__ tact,
    const int* __restrict__ tstate, const int* __restrict__ forc,
    const u16* __restrict__ lut,
    const float* __restrict__ Wm, const float* __restrict__ Wb,
    const float* __restrict__ Ws,
    const float* __restrict__ Mm32, const float* __restrict__ Ms32,
    const float* __restrict__ Mb32, float* __restrict__ out) {
  __shared__ unsigned sPk[TT];          // 2048 B
  __shared__ volatile u16 trajL[TT];    // 1024 B (flag+data in one u16)
  const int tid = threadIdx.x;
  const int b = blockIdx.x;
  for (int t = tid; t < TT; t += 512) {
    const int g = t * BB + b;
    sPk[t] = (unsigned)x[g] | ((unsigned)tact[g] << 8) |
             ((unsigned)tstate[g] << 16) | ((unsigned)forc[g] << 24);
    trajL[t] = 0xFFFFu;
  }
  __syncthreads();  // last barrier; roles diverge below

  const int lane = tid & 63;
  const int w = tid >> 6;

  if (w == 0) {
    // ===== producer: r24 chain verbatim; ds_write IS the publish ========
    __builtin_amdgcn_s_setprio(1);
    int stackv = 0;  // lane i holds stack[i]
    int ptr = 0, rr = 0, s = 0;
    unsigned p0 = sPk[0], p1 = sPk[1], p2 = sPk[2];

    for (int t = 0; t < TT; ++t) {
      const unsigned p3 = sPk[t + 3 < TT ? t + 3 : TT - 1];
      const unsigned pk_s = __builtin_amdgcn_readfirstlane(p0);

      if (lane == 0) trajL[t] = (u16)(s | (rr << 8));  // publish carry-in

      int act, ns;
      if (pk_s >> 24) {  // forced: extract from VGPR p0, no LUT
        act = (int)((p0 >> 8) & 63u);
        ns = (int)((p0 >> 16) & 63u);
      } else {
        const int idx = s * 4096 + rr * 128 + (int)(p0 & 127u);
        const int lv = lut[idx];  // the chain: back-to-back LUT loads
        act = lv & 63;
        ns = (lv >> 6) & 63;
      }

      const bool ispush = act >= 2;
      int npn = ptr + (ispush ? 1 : 0) - (act == 1 ? 1 : 0);
      npn = npn < 0 ? 0 : (npn > 63 ? 63 : npn);
      if (ispush && lane == npn) stackv = act - 2;
      rr = __builtin_amdgcn_ds_bpermute(npn * 4, stackv);
      ptr = npn;
      s = ns;

      p0 = p1; p1 = p2; p2 = p3;
    }
  } else {
    // ======= consumer: 7 waves, rows t = j, j+7, ... ====================
    const int j = w - 1;   // 0..6
    float* outLM = out;                                  // [T,B,34]
    float* outLB = out + (size_t)TT * BB * NMm;          // [T,B,128]
    float* outLS = out + (size_t)TT * BB * (NMm + NBb);  // [T,B,64]

    for (int t = j; t < TT; t += 7) {
      int pr = trajL[t];
      while (pr == 0xFFFF) {            // flag: row not yet published
        __builtin_amdgcn_s_sleep(4);
        pr = trajL[t];
      }
      const unsigned pk = sPk[t];
      const int xv = (int)(pk & 127u);
      const int s = pr & 255;
      const int r = pr >> 8;
      const int rs = 128 + s, rr = 192 + r;
      const int row = t * BB + b;
      if (lane < NMm)
        __builtin_nontemporal_store(
            Mm32[xv * NMm + lane] + Wm[rs * NMm + lane] + Wm[rr * NMm + lane],
            &outLM[(size_t)row * NMm + lane]);
      __builtin_nontemporal_store(
          Ms32[xv * NSs + lane] + Ws[rs * NSs + lane] + Ws[rr * NSs + lane],
          &outLS[(size_t)row * NSs + lane]);
      const f2 mb  = *(const f2*)&Mb32[xv * NBb + 2 * lane];
      const f2 wbs = *(const f2*)&Wb[rs * NBb + 2 * lane];
      const f2 wbr = *(const f2*)&Wb[rr * NBb + 2 * lane];
      f2 o;
      o.x = mb.x + wbs.x + wbr.x;   // same per-element add order as r14-r25
      o.y = mb.y + wbs.y + wbr.y;
      __builtin_nontemporal_store(o, (f2*)&outLB[(size_t)row * NBb + 2 * lane]);
    }
  }
}

extern "C" void kernel_launch(void* const* d_in, const int* in_sizes, int n_in,
                              void* d_out, int out_size, void* d_ws, size_t ws_size,
                              hipStream_t stream) {
  if (ws_size < 690176) return;  // signature: absmax 0.3457 -> ws too small

  const int* x     = (const int*)d_in[0];
  const int* tactp = (const int*)d_in[1];
  const int* tstp  = (const int*)d_in[2];
  const int* forcp = (const int*)d_in[3];
  const float* embed = (const float*)d_in[4];
  const float* Wm = (const float*)d_in[5];
  const float* bm = (const float*)d_in[6];
  const float* Wb = (const float*)d_in[7];
  const float* bb = (const float*)d_in[8];
  const float* Ws = (const float*)d_in[9];
  const float* bs = (const float*)d_in[10];

  char* wsp = (char*)d_ws;
  float* Mm32 = (float*)(wsp);            //  17408 B
  float* Ms32 = (float*)(wsp + 17408);    //  32768 B
  float* Mb32 = (float*)(wsp + 50176);    //  65536 B
  float* MmT  = (float*)(wsp + 115712);   //  17408 B
  float* MsT  = (float*)(wsp + 133120);   //  32768 B
  u16*   lut  = (u16*)(wsp + 165888);     // 524288 B -> total 690176 B

  precompute_M<<<128, 256, 0, stream>>>(embed, Wm, bm, Wb, bb, Ws, bs,
                                        Mm32, Ms32, Mb32, MmT, MsT);
  build_lut<<<2048, 128, 0, stream>>>(Wm, Ws, MmT, MsT, lut);
  sm_fused<<<512, 512, 0, stream>>>(x, tactp, tstp, forcp, lut,
                                    Wm, Wb, Ws, Mm32, Ms32, Mb32,
                                    (float*)d_out);
}